// Round 7
// baseline (215.957 us; speedup 1.0000x reference)
//
#include <hip/hip_runtime.h>
#include <math.h>

#define FEAT_DIM 256
#define NCLS 21
#define TEMP 0.1f
#define BPX 256                 // pixels per batch
#define SPX 64                  // pixels per sub-batch (one wave-width)
#define NW 8                    // waves per block
#define CPW 32                  // channels per wave
#define TSTRIDE 68              // tile row stride (64 px + pad, 16B-aligned rows)

typedef float f32x4 __attribute__((ext_vector_type(4)));
typedef int   i32x4 __attribute__((ext_vector_type(4)));

// ---------------------------------------------------------------------------
// Single-pass fused kernel: reads features from HBM exactly ONCE.
// Key change vs R6: the in-loop barrier is a RAW s_barrier preceded only by
// lgkmcnt(0) — __syncthreads() would drain vmcnt(0) (HIP barrier semantics,
// m97) and kill the prefetch. Prefetch is issued at the TOP of each body so
// the loads stay in flight across the barrier and are covered by a full
// body of compute.
// ---------------------------------------------------------------------------
__global__ __launch_bounds__(512, 1)
void k_fused(const float* __restrict__ feat, const int* __restrict__ lab,
             float* __restrict__ gsum, float* __restrict__ gcnt, int N) {
    __shared__ float        s_tile[NW][CPW * TSTRIDE];   // 69632 B, per-wave
    __shared__ float        s_acc[2 * NCLS * FEAT_DIM];  // 43008 B, cells private
    __shared__ float        s_ssp[2][NW][SPX];           // 4096 B, dbuf partials
    __shared__ float        s_ivr[NW][SPX];              // 2048 B, per-wave iv
    __shared__ unsigned int s_scb[NW][16];               // 512 B, class bytes

    const int tid = threadIdx.x, lane = tid & 63, w = tid >> 6;
    const int c4 = lane >> 4, p16 = lane & 15;           // staging role
    const int h = lane >> 5, chan = lane & 31;           // accumulate role
    const int dbase = w * CPW;
    float* tile = s_tile[w];

    for (int i = tid; i < 2 * NCLS * FEAT_DIM; i += 512) s_acc[i] = 0.f;
    __syncthreads();

    const int nb  = N / BPX;                 // 2304
    const int per = nb / gridDim.x;          // 9
    const int NIT = per * 4;                 // 36 sub-batches per block
    const size_t base0 = (size_t)blockIdx.x * per * BPX;

    float cntacc = 0.f;                      // w0 lane c: running count class c

    float4 VA[8], VB[8];
    int labA = 0, labB = 0;

    // prologue: load sub-batch 0
    {
        labA = lab[base0 + lane];
        #pragma unroll
        for (int j = 0; j < 8; ++j)
            VA[j] = *reinterpret_cast<const float4*>(
                feat + (size_t)(dbase + j * 4 + c4) * N + base0 + 4 * p16);
    }

    auto body = [&](int it, float4 (&VC)[8], int labc,
                    float4 (&VN)[8], int& labn) {
        // ---- 0. prefetch sub-batch it+1 FIRST (covered by this whole body;
        //         the raw barrier below does NOT drain vmcnt)
        if (it + 1 < NIT) {
            const int it2 = it + 1;
            const size_t ns2 = base0 + (size_t)(it2 >> 2) * BPX + (it2 & 3) * SPX;
            labn = lab[ns2 + lane];
            #pragma unroll
            for (int j = 0; j < 8; ++j)
                VN[j] = *reinterpret_cast<const float4*>(
                    feat + (size_t)(dbase + j * 4 + c4) * N + ns2 + 4 * p16);
        }

        // ---- 1. ballot-sort (registers only, identical across waves)
        int myrank = 0, bacc = 0;
        #pragma unroll 1
        for (int c = 0; c < NCLS; ++c) {
            const unsigned long long m = __ballot(labc == c);
            const int cnt = __popcll(m);
            if (labc == c)
                myrank = bacc + __popcll(m & ((1ull << lane) - 1ull));
            if (w == 0 && lane == c) cntacc += (float)cnt;
            bacc += cnt;
        }
        ((unsigned char*)s_scb[w])[myrank] = (unsigned char)labc;

        // ---- 2. in-register squared-norm partials + xor-reduce over c4
        f32x4 ssv = {0.f, 0.f, 0.f, 0.f};
        #pragma unroll
        for (int j = 0; j < 8; ++j) {
            ssv[0] = fmaf(VC[j].x, VC[j].x, ssv[0]);
            ssv[1] = fmaf(VC[j].y, VC[j].y, ssv[1]);
            ssv[2] = fmaf(VC[j].z, VC[j].z, ssv[2]);
            ssv[3] = fmaf(VC[j].w, VC[j].w, ssv[3]);
        }
        #pragma unroll
        for (int i = 0; i < 4; ++i) {
            ssv[i] += __shfl_xor(ssv[i], 16);
            ssv[i] += __shfl_xor(ssv[i], 32);
        }
        if (c4 == 0)
            *(f32x4*)&s_ssp[it & 1][w][4 * p16] = ssv;

        // ---- 3. stage by rank into wave-private tile
        const int r0 = __shfl(myrank, 4 * p16 + 0);
        const int r1 = __shfl(myrank, 4 * p16 + 1);
        const int r2 = __shfl(myrank, 4 * p16 + 2);
        const int r3 = __shfl(myrank, 4 * p16 + 3);
        #pragma unroll
        for (int j = 0; j < 8; ++j) {
            float* trw = tile + (j * 4 + c4) * TSTRIDE;
            trw[r0] = VC[j].x; trw[r1] = VC[j].y;
            trw[r2] = VC[j].z; trw[r3] = VC[j].w;
        }

        // ---- 4. LDS-only fence + RAW barrier (global prefetch stays in flight)
        asm volatile("s_waitcnt lgkmcnt(0)" ::: "memory");
        __builtin_amdgcn_s_barrier();

        // ---- 5. cross-wave norm combine -> iv (wave-private copy, no 2nd bar)
        float ss = 0.f;
        #pragma unroll
        for (int q = 0; q < NW; ++q) ss += s_ssp[it & 1][q][lane];
        s_ivr[w][lane] = 1.0f / fmaxf(sqrtf(ss), 1e-12f);

        // ---- 6. accumulate: lane owns (h, chan); flush = plain private RMW
        f32x4 tv[8], vv[8];
        i32x4 cwv[2];
        const float* trr = tile + chan * TSTRIDE + h * 32;
        const float* pir = s_ivr[w] + h * 32;
        const unsigned int* pcw = s_scb[w] + h * 8;
        #pragma unroll
        for (int j = 0; j < 8; ++j) tv[j] = *(const f32x4*)(trr + 4 * j);
        #pragma unroll
        for (int j = 0; j < 8; ++j) vv[j] = *(const f32x4*)(pir + 4 * j);
        cwv[0] = *(const i32x4*)(pcw);
        cwv[1] = *(const i32x4*)(pcw + 4);

        float acc = 0.f;
        int ccur = cwv[0][0] & 255;
        #pragma unroll
        for (int k = 0; k < 32; ++k) {
            const int word = cwv[k >> 4][(k >> 2) & 3];   // static idx (rule 20)
            const int ck = (word >> (8 * (k & 3))) & 255;
            if (ck != ccur) {
                s_acc[(h * NCLS + ccur) * FEAT_DIM + dbase + chan] += acc;
                acc = 0.f; ccur = ck;
            }
            acc = fmaf(tv[k >> 2][k & 3], vv[k >> 2][k & 3], acc);
        }
        s_acc[(h * NCLS + ccur) * FEAT_DIM + dbase + chan] += acc;
    };

    for (int it = 0; it < NIT; it += 2) {       // NIT=36, even
        body(it,     VA, labA, VB, labB);
        body(it + 1, VB, labB, VA, labA);
    }

    __syncthreads();
    // merge halves -> one global atomic per cell per block; STAGGER start
    // address by blockIdx so concurrent blocks hit disjoint ranges.
    {
        const int total = NCLS * FEAT_DIM;               // 5376
        const int off = (blockIdx.x * 21) % total;
        for (int k = tid; k < total; k += 512) {
            int i = k + off; if (i >= total) i -= total;
            const float v = s_acc[i] + s_acc[total + i];
            if (v != 0.f) atomicAdd(&gsum[i], v);
        }
    }
    if (w == 0 && lane < NCLS) atomicAdd(&gcnt[lane], cntacc);
}

// ---------------------------------------------------------------------------
// Finalize: means -> 21x21 logits -> masked contrastive loss.
// ---------------------------------------------------------------------------
__global__ void k_final(const float* __restrict__ gsum,
                        const float* __restrict__ gcnt,
                        const float* __restrict__ proto,
                        float* __restrict__ out) {
    __shared__ float s_mean[NCLS * 257];
    __shared__ float s_icnt[NCLS];
    __shared__ float s_log[NCLS * NCLS];
    __shared__ float s_term[NCLS];

    if (threadIdx.x < NCLS)
        s_icnt[threadIdx.x] = 1.0f / fmaxf(gcnt[threadIdx.x], 1.0f);
    __syncthreads();

    for (int i = threadIdx.x; i < NCLS * FEAT_DIM; i += blockDim.x) {
        const int c = i / FEAT_DIM, d = i - c * FEAT_DIM;
        s_mean[c * 257 + d] = gsum[i] * s_icnt[c];
    }
    __syncthreads();

    for (int p = threadIdx.x; p < NCLS * NCLS; p += blockDim.x) {
        const int c = p / NCLS, j = p - c * NCLS;
        float acc = 0.f;
        #pragma unroll 8
        for (int d = 0; d < FEAT_DIM; ++d)
            acc += s_mean[c * 257 + d] * proto[j * FEAT_DIM + d];
        s_log[p] = acc / TEMP;
    }
    __syncthreads();

    if (threadIdx.x >= 1 && threadIdx.x < NCLS) {
        const int c = threadIdx.x;
        float m = -INFINITY;
        for (int j = 0; j < NCLS; ++j) m = fmaxf(m, s_log[c * NCLS + j]);
        float den = 0.f;
        for (int j = 1; j < NCLS; ++j) den += expf(s_log[c * NCLS + j] - m);
        s_term[c] = logf(den) - (s_log[c * NCLS + c] - m);
    }
    __syncthreads();

    if (threadIdx.x == 0) {
        float acc = 0.f;
        for (int c = 1; c < NCLS; ++c) acc += s_term[c];
        out[0] = acc / (float)(NCLS - 1);
    }
}

// ---------------------------------------------------------------------------
extern "C" void kernel_launch(void* const* d_in, const int* in_sizes, int n_in,
                              void* d_out, int out_size, void* d_ws, size_t ws_size,
                              hipStream_t stream) {
    const float* feat  = (const float*)d_in[0];
    const float* proto = (const float*)d_in[1];
    const int*   lab   = (const int*)d_in[3];   // d_in[2] "outputs" unused

    const int N = in_sizes[3];                  // 589824 = 2304 * 256

    float* gsum = (float*)d_ws;                 // [21*256]
    float* gcnt = gsum + NCLS * FEAT_DIM;       // [21]

    hipMemsetAsync(gsum, 0, (NCLS * FEAT_DIM + NCLS) * sizeof(float), stream);

    k_fused<<<256, 512, 0, stream>>>(feat, lab, gsum, gcnt, N);
    k_final<<<1, 256, 0, stream>>>(gsum, gcnt, proto, (float*)d_out);
}

// Round 8
// 203.231 us; speedup vs baseline: 1.0626x; 1.0626x over previous
//
#include <hip/hip_runtime.h>
#include <math.h>

#define FEAT_DIM 256
#define NCLS 21
#define TEMP 0.1f
#define SPX 32                  // pixels per sub-batch
#define NW 4                    // waves per block
#define CPW 64                  // channels per wave (lane owns exactly 1)
#define TS 33                   // tile row stride (odd -> uniform-col reads 2-way free)
#define NREP 8                  // gsum replicas (merge-contention split)

typedef float f32x4 __attribute__((ext_vector_type(4)));
typedef int   i32x4 __attribute__((ext_vector_type(4)));

// ---------------------------------------------------------------------------
// Fused single-read kernel. Structure per 32-px sub-batch:
//   w0 ballot-sorts labels (rank/class/perm published in tiny dbuf LDS);
//   all waves: in-register norm partials (shfl_xor over row-groups),
//   LINEAR tile stage (no write-permute), lgkm-fence + RAW s_barrier
//   (global prefetch stays in flight), iv combine, then accumulate:
//   lane owns channel d = w*64+lane, walks 32 rank-ordered pixels via
//   uniform-col tile reads (2-way, free), flushing on (wave-uniform,
//   scalar-branch) class change into a PRIVATE s_acc cell (plain RMW).
// DS budget ~126 slots/wave-sub (~87us/CU) ~= HBM floor (~96us); the
// 2 blocks/CU (LDS 57KB) let the two blocks' phases overlap.
// ---------------------------------------------------------------------------
__global__ __launch_bounds__(256, 2)
void k_fused(const float* __restrict__ feat, const int* __restrict__ lab,
             float* __restrict__ gsum, float* __restrict__ gcnt, int N) {
    __shared__ float s_tile[NW][CPW * TS];                 // 33792 B
    __shared__ float s_acc[NCLS * FEAT_DIM];               // 21504 B
    __shared__ float s_ssp[2][NW][SPX];                    // 1024 B
    __shared__ float s_ivr[NW][SPX];                       // 512 B
    __shared__ alignas(16) unsigned char s_scb[2][SPX];    // 64 B class-by-rank
    __shared__ alignas(16) unsigned char s_prm[2][SPX];    // 64 B px-by-rank

    const int tid = threadIdx.x, lane = tid & 63, w = tid >> 6;
    const int rg = lane >> 3;              // row-group 0..7
    const int pg = lane & 7;               // px-group 0..7 (float4 each)
    const int dbase = w * CPW;
    float* tile = s_tile[w];

    for (int i = tid; i < NCLS * FEAT_DIM; i += 256) s_acc[i] = 0.f;
    __syncthreads();

    const int nsub = N / SPX;              // 18432
    const int per  = nsub / gridDim.x;     // 36 (even)
    const int i0   = blockIdx.x * per;

    float cntacc = 0.f;
    float4 VA[8], VB[8];
    int labA = 0, labB = 0;

    // prologue: sub 0
    {
        const size_t ns = (size_t)i0 * SPX;
        if (w == 0) labA = lab[ns + (lane & 31)];
        #pragma unroll
        for (int j = 0; j < 8; ++j)
            VA[j] = *reinterpret_cast<const float4*>(
                feat + (size_t)(dbase + 8 * j + rg) * N + ns + 4 * pg);
    }

    auto body = [&](int it, float4 (&VC)[8], int labc,
                    float4 (&VN)[8], int& labn) {
        const int buf = it & 1;

        // 0. prefetch it+1 (raw barrier below does NOT drain vmcnt)
        if (it + 1 < per) {
            const size_t ns2 = (size_t)(i0 + it + 1) * SPX;
            if (w == 0) labn = lab[ns2 + (lane & 31)];
            #pragma unroll
            for (int j = 0; j < 8; ++j)
                VN[j] = *reinterpret_cast<const float4*>(
                    feat + (size_t)(dbase + 8 * j + rg) * N + ns2 + 4 * pg);
        }

        // 1. w0 only: ballot-sort 32 labels -> rank tables (dbuf)
        if (w == 0) {
            const int p = lane & 31;
            int myrank = 0, base = 0;
            #pragma unroll 1
            for (int c = 0; c < NCLS; ++c) {
                const unsigned long long m = __ballot(labc == c) & 0xFFFFFFFFull;
                const int cnt = (int)__popcll(m);
                if (labc == c)
                    myrank = base + (int)__popcll(m & ((1ull << p) - 1ull));
                if (lane == c) cntacc += (float)cnt;
                base += cnt;
            }
            if (lane < 32) {
                s_scb[buf][myrank] = (unsigned char)labc;
                s_prm[buf][myrank] = (unsigned char)p;
            }
        }

        // 2. norm partials over this wave's 64 channels; reduce over rg
        {
            f32x4 ssv = {0.f, 0.f, 0.f, 0.f};
            #pragma unroll
            for (int j = 0; j < 8; ++j) {
                ssv[0] = fmaf(VC[j].x, VC[j].x, ssv[0]);
                ssv[1] = fmaf(VC[j].y, VC[j].y, ssv[1]);
                ssv[2] = fmaf(VC[j].z, VC[j].z, ssv[2]);
                ssv[3] = fmaf(VC[j].w, VC[j].w, ssv[3]);
            }
            #pragma unroll
            for (int e = 0; e < 4; ++e) {
                ssv[e] += __shfl_xor(ssv[e], 8);
                ssv[e] += __shfl_xor(ssv[e], 16);
                ssv[e] += __shfl_xor(ssv[e], 32);
            }
            if (rg == 0)
                *reinterpret_cast<f32x4*>(&s_ssp[buf][w][4 * pg]) = ssv;
        }

        // 3. LINEAR stage (no permute at write; ~2-way banks)
        #pragma unroll
        for (int j = 0; j < 8; ++j) {
            float* t = tile + (8 * j + rg) * TS + 4 * pg;
            t[0] = VC[j].x; t[1] = VC[j].y; t[2] = VC[j].z; t[3] = VC[j].w;
        }

        // 4. LDS-only fence + RAW barrier (prefetch stays in flight)
        asm volatile("s_waitcnt lgkmcnt(0)" ::: "memory");
        __builtin_amdgcn_s_barrier();

        // 5. iv by rank (lane r<32 handles rank r; hi lanes duplicate)
        {
            const int r = lane & 31;
            const int px = s_prm[buf][r];
            const float ss = s_ssp[buf][0][px] + s_ssp[buf][1][px] +
                             s_ssp[buf][2][px] + s_ssp[buf][3][px];
            s_ivr[w][r] = 1.0f / fmaxf(sqrtf(ss), 1e-12f);
        }

        // 6. accumulate: lane owns channel d = dbase + lane
        {
            i32x4 pmv[2], scv[2];
            f32x4 vv[8];
            pmv[0] = *reinterpret_cast<const i32x4*>(&s_prm[buf][0]);
            pmv[1] = *reinterpret_cast<const i32x4*>(&s_prm[buf][16]);
            scv[0] = *reinterpret_cast<const i32x4*>(&s_scb[buf][0]);
            scv[1] = *reinterpret_cast<const i32x4*>(&s_scb[buf][16]);
            #pragma unroll
            for (int j = 0; j < 8; ++j)
                vv[j] = *reinterpret_cast<const f32x4*>(&s_ivr[w][4 * j]);

            const float* trow = tile + lane * TS;
            float val[32];
            #pragma unroll
            for (int k = 0; k < 32; ++k) {
                const int px = (pmv[k >> 4][(k >> 2) & 3] >> (8 * (k & 3))) & 255;
                val[k] = trow[px];          // uniform col -> (lane+px)%32, 2-way free
            }

            float acc = 0.f;
            int ccur = __builtin_amdgcn_readfirstlane(scv[0][0] & 255);
            #pragma unroll
            for (int k = 0; k < 32; ++k) {
                const int ck = __builtin_amdgcn_readfirstlane(
                    (scv[k >> 4][(k >> 2) & 3] >> (8 * (k & 3))) & 255);
                if (ck != ccur) {           // wave-uniform scalar branch
                    s_acc[ccur * FEAT_DIM + dbase + lane] += acc;  // private cell
                    acc = 0.f; ccur = ck;
                }
                acc = fmaf(val[k], vv[k >> 2][k & 3], acc);
            }
            s_acc[ccur * FEAT_DIM + dbase + lane] += acc;
        }
    };

    for (int it = 0; it < per; it += 2) {
        body(it,     VA, labA, VB, labB);
        body(it + 1, VB, labB, VA, labA);
    }

    __syncthreads();
    // merge: one atomic per cell into 1-of-8 replicas, block-staggered
    {
        float* grep = gsum + (size_t)(blockIdx.x & (NREP - 1)) * (NCLS * FEAT_DIM);
        const int total = NCLS * FEAT_DIM;
        const int off = (blockIdx.x * 37) % total;
        for (int k = tid; k < total; k += 256) {
            int i = k + off; if (i >= total) i -= total;
            const float v = s_acc[i];
            if (v != 0.f) atomicAdd(&grep[i], v);
        }
    }
    if (w == 0 && lane < NCLS) atomicAdd(&gcnt[lane], cntacc);
}

// ---------------------------------------------------------------------------
// Finalize: sum replicas -> means -> 21x21 logits -> masked loss.
// ---------------------------------------------------------------------------
__global__ void k_final(const float* __restrict__ gsum,
                        const float* __restrict__ gcnt,
                        const float* __restrict__ proto,
                        float* __restrict__ out) {
    __shared__ float s_mean[NCLS * 257];
    __shared__ float s_icnt[NCLS];
    __shared__ float s_log[NCLS * NCLS];
    __shared__ float s_term[NCLS];

    if (threadIdx.x < NCLS)
        s_icnt[threadIdx.x] = 1.0f / fmaxf(gcnt[threadIdx.x], 1.0f);
    __syncthreads();

    for (int i = threadIdx.x; i < NCLS * FEAT_DIM; i += blockDim.x) {
        float v = 0.f;
        #pragma unroll
        for (int r = 0; r < NREP; ++r) v += gsum[r * NCLS * FEAT_DIM + i];
        const int c = i / FEAT_DIM, d = i - c * FEAT_DIM;
        s_mean[c * 257 + d] = v * s_icnt[c];
    }
    __syncthreads();

    for (int p = threadIdx.x; p < NCLS * NCLS; p += blockDim.x) {
        const int c = p / NCLS, j = p - c * NCLS;
        float acc = 0.f;
        #pragma unroll 8
        for (int d = 0; d < FEAT_DIM; ++d)
            acc += s_mean[c * 257 + d] * proto[j * FEAT_DIM + d];
        s_log[p] = acc / TEMP;
    }
    __syncthreads();

    if (threadIdx.x >= 1 && threadIdx.x < NCLS) {
        const int c = threadIdx.x;
        float m = -INFINITY;
        for (int j = 0; j < NCLS; ++j) m = fmaxf(m, s_log[c * NCLS + j]);
        float den = 0.f;
        for (int j = 1; j < NCLS; ++j) den += expf(s_log[c * NCLS + j] - m);
        s_term[c] = logf(den) - (s_log[c * NCLS + c] - m);
    }
    __syncthreads();

    if (threadIdx.x == 0) {
        float acc = 0.f;
        for (int c = 1; c < NCLS; ++c) acc += s_term[c];
        out[0] = acc / (float)(NCLS - 1);
    }
}

// ---------------------------------------------------------------------------
extern "C" void kernel_launch(void* const* d_in, const int* in_sizes, int n_in,
                              void* d_out, int out_size, void* d_ws, size_t ws_size,
                              hipStream_t stream) {
    const float* feat  = (const float*)d_in[0];
    const float* proto = (const float*)d_in[1];
    const int*   lab   = (const int*)d_in[3];   // d_in[2] "outputs" unused

    const int N = in_sizes[3];                  // 589824 = 512 * 36 * 32

    float* gsum = (float*)d_ws;                 // [8][21*256]
    float* gcnt = gsum + NREP * NCLS * FEAT_DIM;

    hipMemsetAsync(gsum, 0,
                   (NREP * NCLS * FEAT_DIM + NCLS) * sizeof(float), stream);

    k_fused<<<512, 256, 0, stream>>>(feat, lab, gsum, gcnt, N);
    k_final<<<1, 256, 0, stream>>>(gsum, gcnt, proto, (float*)d_out);
}